// Round 5
// baseline (15.596 us; speedup 1.0000x reference)
//
#include <hip/hip_runtime.h>

#define P 1024
#define C 8
#define D 8
#define K 8
#define NITER 8            // per-wave a-iterations (each row split across 2 waves)
#define CHUNK 2
#define NCHUNK (NITER / CHUNK)

// out[n,d,b] = sum_{k,c} W[d,c,k] * T[k,c]
// T[k,c]     = sum_a basis_k(r[b,a]) * mask[b,a] * input[c,a]
// basis_k(r) = exp(-8*(r - k*2/7)^2), computed by telescoping:
//   t_0 = 2^64*exp(-8 r^2),  t_k = t_{k-1} * B * q^(2k-1),
//   B = exp(16*(2/7)*r), q = exp(-8*(2/7)^2); mask folded as m*2^-64.
__global__ __launch_bounds__(256, 4) void se3_conv_kernel(
    const float* __restrict__ input,   // [n, C, P]
    const float* __restrict__ diff,    // [n, P, P, 3]
    const float* __restrict__ mask,    // [n, P, P]
    const float* __restrict__ W,       // [D, C, K]
    float* __restrict__ out)           // [n, D, P]
{
    __shared__ float red[4][64];

    const int n    = blockIdx.y;
    const int tid  = threadIdx.x;
    const int lane = tid & 63;
    const int wave = tid >> 6;      // 0..3
    const int rsel = wave >> 1;     // which of this block's 2 rows
    const int half = wave & 1;      // which a-half of the row
    const int b    = blockIdx.x * 2 + rsel;

    const float* diff_row = diff + (((size_t)n * P + b) * P + half * (P / 2)) * 3;
    const float* mask_row = mask + ((size_t)n * P + b) * P + half * (P / 2);
    const float* inp_n    = input + (size_t)n * C * P;

    float acc[K * C];
    #pragma unroll
    for (int i = 0; i < K * C; ++i) acc[i] = 0.0f;

    float xv[NITER], yv[NITER], zv[NITER], mv[NITER];

    // prologue: chunk 0 loads in flight immediately
    #pragma unroll
    for (int j = 0; j < CHUNK; ++j) {
        const float* p = diff_row + (size_t)(lane + j * 64) * 3;
        xv[j] = p[0]; yv[j] = p[1]; zv[j] = p[2];
        mv[j] = mask_row[lane + j * 64];
    }

    const float C_R2 = -11.5415603f;   // -8*log2(e)
    const float C_R  = 6.5951774f;     // 16*(2/7)*log2(e)
    const float cq[K - 1] = {           // q^(2k-1), q = exp(-8*(2/7)^2)
        0.5204502f, 0.1409736f, 0.0381853f, 0.0103432f,
        0.00280164f, 0.00075888f, 0.00020556f};

    #pragma unroll
    for (int ch = 0; ch < NCHUNK; ++ch) {
        // issue next chunk's global loads; no barrier, counted waits
        if (ch + 1 < NCHUNK) {
            #pragma unroll
            for (int jj = 0; jj < CHUNK; ++jj) {
                const int j = (ch + 1) * CHUNK + jj;
                const float* p = diff_row + (size_t)(lane + j * 64) * 3;
                xv[j] = p[0]; yv[j] = p[1]; zv[j] = p[2];
                mv[j] = mask_row[lane + j * 64];
            }
        }

        #pragma unroll
        for (int jj = 0; jj < CHUNK; ++jj) {
            const int j = ch * CHUNK + jj;
            const int a = half * (P / 2) + j * 64 + lane;

            float inp[C];   // coalesced, L1/L2-hot
            #pragma unroll
            for (int c = 0; c < C; ++c) inp[c] = inp_n[c * P + a];

            const float x = xv[j], y = yv[j], z = zv[j];
            const float r2 = fmaf(x, x, fmaf(y, y, z * z));
            const float r  = __builtin_amdgcn_sqrtf(r2);
            float t        = __builtin_amdgcn_exp2f(fmaf(C_R2, r2, 64.0f));
            const float B  = __builtin_amdgcn_exp2f(C_R * r);
            const float mp = mv[j] * 0x1p-64f;

            #pragma unroll
            for (int k = 0; k < K; ++k) {
                const float bm = t * mp;
                #pragma unroll
                for (int c = 0; c < C; ++c)
                    acc[k * C + c] = fmaf(bm, inp[c], acc[k * C + c]);
                if (k < K - 1) t = t * (B * cq[k]);
            }
        }
    }

    // ---- wave-level reduce-scatter (recursive halving) ----
    // After 6 steps lane l holds the wave-total of acc[bitrev6(l)].
    #pragma unroll
    for (int s = 0; s < 6; ++s) {
        const int hw  = 32 >> s;
        const int bit = (lane >> s) & 1;
        #pragma unroll
        for (int i = 0; i < hw; ++i) {
            const float send = bit ? acc[i] : acc[i + hw];
            const float recv = __shfl_xor(send, 1 << s, 64);
            const float keep = bit ? acc[i + hw] : acc[i];
            acc[i] = keep + recv;
        }
    }

    const int j64 = (int)(__brev((unsigned)lane) >> 26);  // bitrev6(lane)
    red[wave][j64] = acc[0];
    __syncthreads();

    // ---- combine the row's two waves + W contraction: lane = d*8+k ----
    if (half == 0) {
        const int d  = lane >> 3;
        const int k8 = lane & 7;
        float part = 0.0f;
        #pragma unroll
        for (int c = 0; c < C; ++c)
            part += W[d * 64 + c * 8 + k8] *
                    (red[wave][k8 * 8 + c] + red[wave + 1][k8 * 8 + c]);
        part += __shfl_xor(part, 1, 64);
        part += __shfl_xor(part, 2, 64);
        part += __shfl_xor(part, 4, 64);
        if (k8 == 0)
            out[((size_t)n * D + d) * P + b] = part;
    }
}

extern "C" void kernel_launch(void* const* d_in, const int* in_sizes, int n_in,
                              void* d_out, int out_size, void* d_ws, size_t ws_size,
                              hipStream_t stream) {
    const float* input = (const float*)d_in[0];   // [2, 8, 1024]
    const float* diff  = (const float*)d_in[1];   // [2, 1024, 1024, 3]
    const float* mask  = (const float*)d_in[2];   // [2, 1024, 1024]
    const float* W     = (const float*)d_in[3];   // [8, 8, 8]
    float* out = (float*)d_out;                   // [2, 8, 1024]

    dim3 grid(P / 2, 2);
    se3_conv_kernel<<<grid, 256, 0, stream>>>(input, diff, mask, W, out);
}